// Round 2
// baseline (164.854 us; speedup 1.0000x reference)
//
#include <hip/hip_runtime.h>

typedef unsigned short u16;
typedef unsigned int   u32;
typedef __attribute__((ext_vector_type(8))) short          shortx8;
typedef __attribute__((ext_vector_type(8))) unsigned short ushortx8;
typedef __attribute__((ext_vector_type(4))) float          floatx4;

#define AS1 __attribute__((address_space(1)))
#define AS3 __attribute__((address_space(3)))

#define SEG 8208   // 8192 + 16 pad cols per batch segment of Vt
#define LV  16416  // 2 * SEG

__device__ __forceinline__ float b2f(u16 v) {
  return __uint_as_float(((u32)v) << 16);
}
__device__ __forceinline__ u16 f2b(float f) {
  u32 u = __float_as_uint(f);
  u += 0x7FFF + ((u >> 16) & 1);   // RNE
  return (u16)(u >> 16);
}
__device__ __forceinline__ void cp16(const void* g, void* l) {
  // 16B/lane global->LDS DMA; LDS dest must be wave-uniform base + lane*16
  __builtin_amdgcn_global_load_lds((AS1 u32*)g, (AS3 u32*)l, 16, 0, 0);
}

// ---------------------------------------------------------------------------
// Fused prep: [0,4096) cast+width rows; [4096,4864) transpose w_qkv;
// [4864,5120) transpose w_out; [5120,5184) Vt pad-zeroing.
__global__ __launch_bounds__(256)
void prep(const float* __restrict__ x, const float* __restrict__ w_width,
          const float* __restrict__ b_width, const float* __restrict__ w_qkv,
          const float* __restrict__ w_out, u16* __restrict__ xb,
          float* __restrict__ width, u16* __restrict__ wqkvT,
          u16* __restrict__ woutT, u16* __restrict__ Vt) {
  __shared__ u16 tile[32][33];
  const int b = blockIdx.x;
  if (b < 4096) {                    // ---- cast x -> bf16, compute width
    const int lane = threadIdx.x & 63;
    const int row  = b * 4 + (threadIdx.x >> 6);
    const float* xp = x + (size_t)row * 512 + lane * 8;
    floatx4 v0 = *(const floatx4*)xp;
    floatx4 v1 = *(const floatx4*)(xp + 4);
    floatx4 w0 = *(const floatx4*)(w_width + lane * 8);
    floatx4 w1 = *(const floatx4*)(w_width + lane * 8 + 4);
    float s = 0.f;
    ushortx8 o;
#pragma unroll
    for (int j = 0; j < 4; ++j) {
      s += v0[j] * w0[j] + v1[j] * w1[j];
      o[j] = f2b(v0[j]); o[4 + j] = f2b(v1[j]);
    }
    *(ushortx8*)(xb + (size_t)row * 512 + lane * 8) = o;
#pragma unroll
    for (int m = 32; m >= 1; m >>= 1) s += __shfl_xor(s, m, 64);
    if (lane == 0)
      width[row] = 16.f / (1.f + __expf(-(s + b_width[0]))) + 1.f;
  } else if (b < 5120) {             // ---- weight transposes (fp32 -> bf16^T)
    const float* in; u16* out; int R, C, t;
    if (b < 4864) { in = w_qkv; out = wqkvT; R = 512; C = 1536; t = b - 4096; }
    else          { in = w_out; out = woutT; R = 512; C = 512;  t = b - 4864; }
    const int nbx = C / 32;
    const int cb = (t % nbx) * 32;
    const int rb = (t / nbx) * 32;
    const int tx = threadIdx.x & 31;
    const int ty = threadIdx.x >> 5;
#pragma unroll
    for (int i = 0; i < 32; i += 8)
      tile[ty + i][tx] = f2b(in[(size_t)(rb + ty + i) * C + cb + tx]);
    __syncthreads();
#pragma unroll
    for (int i = 0; i < 32; i += 8)
      out[(size_t)(cb + ty + i) * R + rb + tx] = tile[tx][ty + i];
  } else {                           // ---- Vt pad-column zeroing
    const int idx = (b - 5120) * 256 + threadIdx.x;  // 512 ch * 32 pad cols
    const int ch = idx >> 5;
    const int k  = idx & 31;
    const int seg = k >> 4;
    const int j   = k & 15;
    const int col = seg * SEG + (j < 8 ? j : 8192 + j);
    Vt[(size_t)ch * LV + col] = 0;
  }
}

// ---------------------------------------------------------------------------
// C = A[M][512] @ Bt[N][512]^T, bf16 in, fp32 acc.  128x128 tile, BK=64,
// XOR-swizzled LDS staging, LDS-shuffled coalesced epilogues.
// MODE 1: N=1536, scatter epilogue -> Qb / Kb / Vt(transposed, batch-padded).
// MODE 2: N=512,  fp32 C (ldc=512), direct stores.  (unused after proj fusion)
template <int MODE>
__global__ __launch_bounds__(256, 3)
void gemm_bt(const u16* __restrict__ A, const u16* __restrict__ Bt,
             void* __restrict__ C0, u16* __restrict__ Kb, u16* __restrict__ Vt) {
  const int K = 512;
  __shared__ alignas(16) u16 lds[17408];        // 34,816 B (union)
  u16* As = lds;                                // 8192 u16 (128 x 64)
  u16* Bs = lds + 8192;                         // 8192 u16
  const int tid  = threadIdx.x;
  const int lane = tid & 63;
  const int wave = tid >> 6;
  const int quad = lane >> 4;
  const int lr   = lane & 15;
  const int row0 = blockIdx.x * 128;
  const int col0 = blockIdx.y * 128;
  const int wr   = (wave >> 1) * 64;
  const int wc   = (wave & 1) * 64;

  floatx4 acc[4][4];
#pragma unroll
  for (int i = 0; i < 4; ++i)
#pragma unroll
    for (int j = 0; j < 4; ++j) acc[i][j] = (floatx4)0.0f;

  // chunk c = p*256+tid -> LDS slot c; row c>>3, phys colblk (c&7)^(row&7)
  int srow[4], scol[4];
#pragma unroll
  for (int p = 0; p < 4; ++p) {
    int c = p * 256 + tid;
    srow[p] = c >> 3;
    scol[p] = ((c & 7) ^ (srow[p] & 7)) * 8;
  }
  const int swz = lr & 7;

  for (int k0 = 0; k0 < K; k0 += 64) {
#pragma unroll
    for (int p = 0; p < 4; ++p)
      cp16(A + (size_t)(row0 + srow[p]) * K + k0 + scol[p], &As[(p * 256 + tid) * 8]);
#pragma unroll
    for (int p = 0; p < 4; ++p)
      cp16(Bt + (size_t)(col0 + srow[p]) * K + k0 + scol[p], &Bs[(p * 256 + tid) * 8]);
    __syncthreads();

#pragma unroll
    for (int ks = 0; ks < 2; ++ks) {
      shortx8 af[4], bf[4];
#pragma unroll
      for (int mi = 0; mi < 4; ++mi)
        af[mi] = *(const shortx8*)
            &As[((wr + mi * 16 + lr) * 8 + ((ks * 4 + quad) ^ swz)) * 8];
#pragma unroll
      for (int ni = 0; ni < 4; ++ni)
        bf[ni] = *(const shortx8*)
            &Bs[((wc + ni * 16 + lr) * 8 + ((ks * 4 + quad) ^ swz)) * 8];
#pragma unroll
      for (int mi = 0; mi < 4; ++mi)
#pragma unroll
        for (int ni = 0; ni < 4; ++ni)
          acc[mi][ni] = __builtin_amdgcn_mfma_f32_16x16x32_bf16(
              af[mi], bf[ni], acc[mi][ni], 0, 0, 0);
    }
    __syncthreads();
  }

  // C/D layout: col = lane&15, row = quad*4 + reg  [verified m89/m91]
  if constexpr (MODE == 1) {
    if (col0 < 1024) {               // ---- Q or K: row-major LDS, coalesced out
      u16* dst = (col0 < 512) ? (u16*)C0 : Kb;
      const int cb = col0 & 511;
#pragma unroll
      for (int mi = 0; mi < 4; ++mi)
#pragma unroll
        for (int ni = 0; ni < 4; ++ni)
#pragma unroll
          for (int r = 0; r < 4; ++r)
            lds[(wr + mi * 16 + quad * 4 + r) * 136 + wc + ni * 16 + lr] =
                f2b(acc[mi][ni][r]);
      __syncthreads();
      const int rr = tid >> 4, cc = (tid & 15) * 8;
#pragma unroll
      for (int it = 0; it < 8; ++it) {
        int row = it * 16 + rr;
        *(ushortx8*)(dst + (size_t)(row0 + row) * 512 + cb + cc) =
            *(const ushortx8*)&lds[row * 136 + cc];
      }
    } else {                         // ---- V: transposed LDS, coalesced out
      const int cb = col0 - 1024;
      const int bb = row0 >> 13, pib0 = row0 & 8191;
#pragma unroll
      for (int mi = 0; mi < 4; ++mi)
#pragma unroll
        for (int ni = 0; ni < 4; ++ni)
#pragma unroll
          for (int r = 0; r < 4; ++r)
            lds[(wc + ni * 16 + lr) * 136 + wr + mi * 16 + quad * 4 + r] =
                f2b(acc[mi][ni][r]);
      __syncthreads();
      const int rr = tid >> 4, cc = (tid & 15) * 8;
#pragma unroll
      for (int it = 0; it < 8; ++it) {
        int chl = it * 16 + rr;
        ushortx8 v = *(const ushortx8*)&lds[chl * 136 + cc];
        *(ushortx8*)(Vt + (size_t)(cb + chl) * LV + (size_t)bb * SEG + 8 + pib0 + cc) = v;
      }
    }
  } else {
    float* Cf = (float*)C0;
#pragma unroll
    for (int mi = 0; mi < 4; ++mi)
#pragma unroll
      for (int ni = 0; ni < 4; ++ni)
#pragma unroll
        for (int r = 0; r < 4; ++r) {
          int row = row0 + wr + mi * 16 + quad * 4 + r;
          int col = col0 + wc + ni * 16 + lr;
          Cf[(size_t)row * 512 + col] = acc[mi][ni][r];
        }
  }
}

// ---------------------------------------------------------------------------
// Fused local attention + output projection, v2.
// 32 positions/block, 512 blocks (2 blocks/CU -> 2 waves/SIMD; v1's 256
// blocks = 1 wave/SIMD exposed all MFMA/LDS/L2 latency serially).
// Wave w = (rg = w&1, tw = w>>1):
//   Phase A: complete scores for row-group rg, K-window tw, over ALL 512
//            channels (no split-K partials) -> S[32][32] f32 in LDS.
//   Softmax: thread row = tid>>3, 4 cols; 8-lane shfl reduce; P[32][40] bf16.
//   PV:      wave covers rows rg x channels [tw*256, +256) -> Osw (32KB,
//            XOR-chunk-swizzled for conflict-free proj A-reads).
//   Proj:    wave computes out[32 x 128] at cols w*128, full K=512.
// "+v" residual folded into P's self slot; woutT stays L2-resident.
__global__ __launch_bounds__(256, 2)
void attn_fused(const u16* __restrict__ Q, const u16* __restrict__ Kb,
                const u16* __restrict__ Vt, const float* __restrict__ width,
                const u16* __restrict__ woutT, float* __restrict__ Out) {
  __shared__ alignas(16) u16 Osw[32 * 512];   // 32KB O, row-chunk-swizzled
  __shared__ float S[32][33];                 // scores (pad 33: bank-spread)
  __shared__ u16 P[32][40];                   // probs (pad 40: b128-read spread)
  const int tid  = threadIdx.x;
  const int lane = tid & 63;
  const int wave = tid >> 6;
  const int quad = lane >> 4;
  const int lr   = lane & 15;
  const int p0   = blockIdx.x * 32;
  const int rg   = wave & 1;       // row-group (16 rows)
  const int tw   = wave >> 1;      // phase A: K-window; PV: channel half
  const int prg  = p0 + rg * 16;
  const int pib  = prg & 8191;
  const int bb   = prg >> 13;

  // ---- Phase A: scores rows [prg,prg+16) x window tw, all 512 channels
  floatx4 s0 = (floatx4)0.0f;
#pragma unroll 4
  for (int s = 0; s < 16; ++s) {
    const int k0 = s * 32 + quad * 8;
    shortx8 af = *(const shortx8*)(Q  + (size_t)(prg + lr) * 512 + k0);
    shortx8 f  = *(const shortx8*)(Kb +
                   (ptrdiff_t)(prg - 8 + tw * 16 + lr) * 512 + k0);
    s0 = __builtin_amdgcn_mfma_f32_16x16x32_bf16(af, f, s0, 0, 0, 0);
  }
#pragma unroll
  for (int r = 0; r < 4; ++r)
    S[rg * 16 + quad * 4 + r][tw * 16 + lr] = s0[r];
  __syncthreads();

  // ---- softmax: row = tid>>3 (0..31), cols {cg, cg+8, cg+16, cg+24}
  {
    const int row = tid >> 3, cg = tid & 7;
    const int rr  = row & 15;                       // row within its group
    const int pibr = (p0 + (row >> 4) * 16) & 8191; // group batch offset
    const float scale = 0.044194173824159216f;      // 512^-0.5
    const float wrow = width[p0 + row];
    float sv[4]; float mx = -1e30f;
#pragma unroll
    for (int t = 0; t < 4; ++t) {
      const int col = t * 8 + cg;
      const int d  = col - rr;            // window slot 0..16 when in band
      const int jb = pibr + col - 8;      // k position within batch
      float rel = fabsf((float)(d - 8));
      float msk = 1.f / (1.f + __expf(-5.f * (wrow - rel)));
      float pen = (1.f - msk) * 10000.f;
      float val = (d >= 0 && d <= 16)
          ? (((unsigned)jb < 8192u ? S[row][col] * scale : 0.f) - pen)
          : -1e30f;
      sv[t] = val; mx = fmaxf(mx, val);
    }
#pragma unroll
    for (int m = 4; m >= 1; m >>= 1) mx = fmaxf(mx, __shfl_xor(mx, m, 64));
    float e[4], sum = 0.f;
#pragma unroll
    for (int t = 0; t < 4; ++t) { e[t] = __expf(sv[t] - mx); sum += e[t]; }
#pragma unroll
    for (int m = 4; m >= 1; m >>= 1) sum += __shfl_xor(sum, m, 64);
    const float inv = 1.f / sum;
#pragma unroll
    for (int t = 0; t < 4; ++t) {
      const int col = t * 8 + cg;
      // +1 at the self slot (d==8) folds the "+ v" into PV
      P[row][col] = f2b(e[t] * inv + ((col - rr) == 8 ? 1.f : 0.f));
    }
  }
  __syncthreads();

  // ---- PV: wave (rg, tw): rows rg x channels [tw*256, tw*256+256)
  shortx8 pf = *(const shortx8*)&P[rg * 16 + lr][quad * 8];
  const size_t cb0 = (size_t)bb * SEG + pib;        // Vt col of window slot 0
#pragma unroll 4
  for (int ctl = 0; ctl < 16; ++ctl) {
    const int ch = tw * 256 + ctl * 16 + lr;
    shortx8 vf = *(const shortx8*)(Vt + (size_t)ch * LV + cb0 + quad * 8);
    floatx4 o = __builtin_amdgcn_mfma_f32_16x16x32_bf16(pf, vf, (floatx4)0.0f,
                                                        0, 0, 0);
    const int c = tw * 32 + ctl * 2 + (lr >> 3);    // 16B chunk 0..63
#pragma unroll
    for (int r = 0; r < 4; ++r) {
      const int row = rg * 16 + quad * 4 + r;
      Osw[row * 512 + (((c & ~7) | ((c & 7) ^ (row & 7))) << 3) + (lr & 7)] =
          f2b(o[r]);
    }
  }
  __syncthreads();

  // ---- projection: wave -> out[32 x 128] at cols wave*128, K = 512
  const int wc = wave * 128;
  floatx4 acc[2][8];
#pragma unroll
  for (int mi = 0; mi < 2; ++mi)
#pragma unroll
    for (int ni = 0; ni < 8; ++ni) acc[mi][ni] = (floatx4)0.0f;

  for (int ksl = 0; ksl < 16; ++ksl) {
    const int kg = ksl * 32 + quad * 8;
    shortx8 bfr[8], afr[2];
#pragma unroll
    for (int ni = 0; ni < 8; ++ni)
      bfr[ni] = *(const shortx8*)(woutT + (size_t)(wc + ni * 16 + lr) * 512 + kg);
#pragma unroll
    for (int mi = 0; mi < 2; ++mi) {
      const int row = mi * 16 + lr;
      const int c = ksl * 4 + quad;
      afr[mi] = *(const shortx8*)
          &Osw[row * 512 + (((c & ~7) | ((c & 7) ^ (row & 7))) << 3)];
    }
#pragma unroll
    for (int mi = 0; mi < 2; ++mi)
#pragma unroll
      for (int ni = 0; ni < 8; ++ni)
        acc[mi][ni] = __builtin_amdgcn_mfma_f32_16x16x32_bf16(
            afr[mi], bfr[ni], acc[mi][ni], 0, 0, 0);
  }

  // ---- epilogue: direct fp32 stores (row=mi*16+quad*4+r, col=wc+ni*16+lr)
#pragma unroll
  for (int mi = 0; mi < 2; ++mi)
#pragma unroll
    for (int ni = 0; ni < 8; ++ni)
#pragma unroll
      for (int r = 0; r < 4; ++r)
        Out[(size_t)(p0 + mi * 16 + quad * 4 + r) * 512 + wc + ni * 16 + lr] =
            acc[mi][ni][r];
}

// ---------------------------------------------------------------------------
extern "C" void kernel_launch(void* const* d_in, const int* in_sizes, int n_in,
                              void* d_out, int out_size, void* d_ws, size_t ws_size,
                              hipStream_t stream) {
  const float* x       = (const float*)d_in[0];  // [2,8192,512] fp32
  const float* w_qkv   = (const float*)d_in[1];  // [512,1536]  fp32
  const float* w_width = (const float*)d_in[2];  // [512,1]     fp32
  const float* b_width = (const float*)d_in[3];  // [1]         fp32
  const float* w_out   = (const float*)d_in[4];  // [512,512]   fp32
  float* out = (float*)d_out;                    // [2,8192,512] fp32

  const int M = 16384, N3 = 1536;
  char* ws = (char*)d_ws;
  u16*   xb    = (u16*)(ws);                       // 16,777,216
  u16*   Qb    = (u16*)(ws + 16777216);            // 16,777,216
  u16*   Kb    = (u16*)(ws + 33554432 + 8192);     // 8KB guard | 16.7MB | guard
  u16*   Vt    = (u16*)(ws + 50348032);            // 512*16416*2 = 16,809,984
  u16*   wqkvT = (u16*)(ws + 67158016);            //  1,572,864
  u16*   woutT = (u16*)(ws + 68730880);            //    524,288
  float* width = (float*)(ws + 69255168);          //     65,536

  dim3 blk(256);
  prep<<<dim3(5184), blk, 0, stream>>>(x, w_width, b_width, w_qkv, w_out,
                                       xb, width, wqkvT, woutT, Vt);
  gemm_bt<1><<<dim3(M / 128, N3 / 128), blk, 0, stream>>>(xb, wqkvT, Qb, Kb, Vt);
  attn_fused<<<dim3(M / 32), blk, 0, stream>>>(Qb, Kb, Vt, width, woutT, out);
}

// Round 3
// 164.547 us; speedup vs baseline: 1.0019x; 1.0019x over previous
//
#include <hip/hip_runtime.h>

typedef unsigned short u16;
typedef unsigned int   u32;
typedef __attribute__((ext_vector_type(8))) short          shortx8;
typedef __attribute__((ext_vector_type(8))) unsigned short ushortx8;
typedef __attribute__((ext_vector_type(4))) float          floatx4;

#define AS1 __attribute__((address_space(1)))
#define AS3 __attribute__((address_space(3)))

#define SEG 8208   // 8192 + 16 pad cols per batch segment of Vt
#define LV  16416  // 2 * SEG

__device__ __forceinline__ float b2f(u16 v) {
  return __uint_as_float(((u32)v) << 16);
}
__device__ __forceinline__ u16 f2b(float f) {
  u32 u = __float_as_uint(f);
  u += 0x7FFF + ((u >> 16) & 1);   // RNE
  return (u16)(u >> 16);
}
__device__ __forceinline__ void cp16(const void* g, void* l) {
  // 16B/lane global->LDS DMA; LDS dest must be wave-uniform base + lane*16
  __builtin_amdgcn_global_load_lds((AS1 u32*)g, (AS3 u32*)l, 16, 0, 0);
}

// ---------------------------------------------------------------------------
// Fused prep: [0,4096) cast+width rows; [4096,4864) transpose w_qkv;
// [4864,5120) transpose w_out; [5120,5184) Vt pad-zeroing.
__global__ __launch_bounds__(256)
void prep(const float* __restrict__ x, const float* __restrict__ w_width,
          const float* __restrict__ b_width, const float* __restrict__ w_qkv,
          const float* __restrict__ w_out, u16* __restrict__ xb,
          float* __restrict__ width, u16* __restrict__ wqkvT,
          u16* __restrict__ woutT, u16* __restrict__ Vt) {
  __shared__ u16 tile[32][33];
  const int b = blockIdx.x;
  if (b < 4096) {                    // ---- cast x -> bf16, compute width
    const int lane = threadIdx.x & 63;
    const int row  = b * 4 + (threadIdx.x >> 6);
    const float* xp = x + (size_t)row * 512 + lane * 8;
    floatx4 v0 = *(const floatx4*)xp;
    floatx4 v1 = *(const floatx4*)(xp + 4);
    floatx4 w0 = *(const floatx4*)(w_width + lane * 8);
    floatx4 w1 = *(const floatx4*)(w_width + lane * 8 + 4);
    float s = 0.f;
    ushortx8 o;
#pragma unroll
    for (int j = 0; j < 4; ++j) {
      s += v0[j] * w0[j] + v1[j] * w1[j];
      o[j] = f2b(v0[j]); o[4 + j] = f2b(v1[j]);
    }
    *(ushortx8*)(xb + (size_t)row * 512 + lane * 8) = o;
#pragma unroll
    for (int m = 32; m >= 1; m >>= 1) s += __shfl_xor(s, m, 64);
    if (lane == 0)
      width[row] = 16.f / (1.f + __expf(-(s + b_width[0]))) + 1.f;
  } else if (b < 5120) {             // ---- weight transposes (fp32 -> bf16^T)
    const float* in; u16* out; int R, C, t;
    if (b < 4864) { in = w_qkv; out = wqkvT; R = 512; C = 1536; t = b - 4096; }
    else          { in = w_out; out = woutT; R = 512; C = 512;  t = b - 4864; }
    const int nbx = C / 32;
    const int cb = (t % nbx) * 32;
    const int rb = (t / nbx) * 32;
    const int tx = threadIdx.x & 31;
    const int ty = threadIdx.x >> 5;
#pragma unroll
    for (int i = 0; i < 32; i += 8)
      tile[ty + i][tx] = f2b(in[(size_t)(rb + ty + i) * C + cb + tx]);
    __syncthreads();
#pragma unroll
    for (int i = 0; i < 32; i += 8)
      out[(size_t)(cb + ty + i) * R + rb + tx] = tile[tx][ty + i];
  } else {                           // ---- Vt pad-column zeroing
    const int idx = (b - 5120) * 256 + threadIdx.x;  // 512 ch * 32 pad cols
    const int ch = idx >> 5;
    const int k  = idx & 31;
    const int seg = k >> 4;
    const int j   = k & 15;
    const int col = seg * SEG + (j < 8 ? j : 8192 + j);
    Vt[(size_t)ch * LV + col] = 0;
  }
}

// ---------------------------------------------------------------------------
// C = A[M][512] @ Bt[N][512]^T, bf16 in, fp32 acc.  128x128 tile, BK=64,
// XOR-swizzled LDS staging, LDS-shuffled coalesced epilogues.
// MODE 1: N=1536, scatter epilogue -> Qb / Kb / Vt(transposed, batch-padded).
// MODE 2: N=512,  fp32 C (ldc=512), direct stores.  (unused after proj fusion)
template <int MODE>
__global__ __launch_bounds__(256, 3)
void gemm_bt(const u16* __restrict__ A, const u16* __restrict__ Bt,
             void* __restrict__ C0, u16* __restrict__ Kb, u16* __restrict__ Vt) {
  const int K = 512;
  __shared__ alignas(16) u16 lds[17408];        // 34,816 B (union)
  u16* As = lds;                                // 8192 u16 (128 x 64)
  u16* Bs = lds + 8192;                         // 8192 u16
  const int tid  = threadIdx.x;
  const int lane = tid & 63;
  const int wave = tid >> 6;
  const int quad = lane >> 4;
  const int lr   = lane & 15;
  const int row0 = blockIdx.x * 128;
  const int col0 = blockIdx.y * 128;
  const int wr   = (wave >> 1) * 64;
  const int wc   = (wave & 1) * 64;

  floatx4 acc[4][4];
#pragma unroll
  for (int i = 0; i < 4; ++i)
#pragma unroll
    for (int j = 0; j < 4; ++j) acc[i][j] = (floatx4)0.0f;

  // chunk c = p*256+tid -> LDS slot c; row c>>3, phys colblk (c&7)^(row&7)
  int srow[4], scol[4];
#pragma unroll
  for (int p = 0; p < 4; ++p) {
    int c = p * 256 + tid;
    srow[p] = c >> 3;
    scol[p] = ((c & 7) ^ (srow[p] & 7)) * 8;
  }
  const int swz = lr & 7;

  for (int k0 = 0; k0 < K; k0 += 64) {
#pragma unroll
    for (int p = 0; p < 4; ++p)
      cp16(A + (size_t)(row0 + srow[p]) * K + k0 + scol[p], &As[(p * 256 + tid) * 8]);
#pragma unroll
    for (int p = 0; p < 4; ++p)
      cp16(Bt + (size_t)(col0 + srow[p]) * K + k0 + scol[p], &Bs[(p * 256 + tid) * 8]);
    __syncthreads();

#pragma unroll
    for (int ks = 0; ks < 2; ++ks) {
      shortx8 af[4], bf[4];
#pragma unroll
      for (int mi = 0; mi < 4; ++mi)
        af[mi] = *(const shortx8*)
            &As[((wr + mi * 16 + lr) * 8 + ((ks * 4 + quad) ^ swz)) * 8];
#pragma unroll
      for (int ni = 0; ni < 4; ++ni)
        bf[ni] = *(const shortx8*)
            &Bs[((wc + ni * 16 + lr) * 8 + ((ks * 4 + quad) ^ swz)) * 8];
#pragma unroll
      for (int mi = 0; mi < 4; ++mi)
#pragma unroll
        for (int ni = 0; ni < 4; ++ni)
          acc[mi][ni] = __builtin_amdgcn_mfma_f32_16x16x32_bf16(
              af[mi], bf[ni], acc[mi][ni], 0, 0, 0);
    }
    __syncthreads();
  }

  // C/D layout: col = lane&15, row = quad*4 + reg  [verified m89/m91]
  if constexpr (MODE == 1) {
    if (col0 < 1024) {               // ---- Q or K: row-major LDS, coalesced out
      u16* dst = (col0 < 512) ? (u16*)C0 : Kb;
      const int cb = col0 & 511;
#pragma unroll
      for (int mi = 0; mi < 4; ++mi)
#pragma unroll
        for (int ni = 0; ni < 4; ++ni)
#pragma unroll
          for (int r = 0; r < 4; ++r)
            lds[(wr + mi * 16 + quad * 4 + r) * 136 + wc + ni * 16 + lr] =
                f2b(acc[mi][ni][r]);
      __syncthreads();
      const int rr = tid >> 4, cc = (tid & 15) * 8;
#pragma unroll
      for (int it = 0; it < 8; ++it) {
        int row = it * 16 + rr;
        *(ushortx8*)(dst + (size_t)(row0 + row) * 512 + cb + cc) =
            *(const ushortx8*)&lds[row * 136 + cc];
      }
    } else {                         // ---- V: transposed LDS, coalesced out
      const int cb = col0 - 1024;
      const int bb = row0 >> 13, pib0 = row0 & 8191;
#pragma unroll
      for (int mi = 0; mi < 4; ++mi)
#pragma unroll
        for (int ni = 0; ni < 4; ++ni)
#pragma unroll
          for (int r = 0; r < 4; ++r)
            lds[(wc + ni * 16 + lr) * 136 + wr + mi * 16 + quad * 4 + r] =
                f2b(acc[mi][ni][r]);
      __syncthreads();
      const int rr = tid >> 4, cc = (tid & 15) * 8;
#pragma unroll
      for (int it = 0; it < 8; ++it) {
        int chl = it * 16 + rr;
        ushortx8 v = *(const ushortx8*)&lds[chl * 136 + cc];
        *(ushortx8*)(Vt + (size_t)(cb + chl) * LV + (size_t)bb * SEG + 8 + pib0 + cc) = v;
      }
    }
  } else {
    float* Cf = (float*)C0;
#pragma unroll
    for (int mi = 0; mi < 4; ++mi)
#pragma unroll
      for (int ni = 0; ni < 4; ++ni)
#pragma unroll
        for (int r = 0; r < 4; ++r) {
          int row = row0 + wr + mi * 16 + quad * 4 + r;
          int col = col0 + wc + ni * 16 + lr;
          Cf[(size_t)row * 512 + col] = acc[mi][ni][r];
        }
  }
}

// ---------------------------------------------------------------------------
// Fused local attention + output projection, v3.
// 32 positions/block, 512 blocks, **512 threads (8 waves)** -> 2 blocks/CU x
// 8 waves = 16 waves/CU (v2's 4-wave blocks capped at 8 waves/CU; MfmaUtil
// was 6.5% with ~90% stall).  Work split, wave w:
//   Phase A: (rg=w&1, tw=(w>>1)&1, kh=w>>2): rows rg, score-cols tw*16,
//            channels kh*256: 8 MFMA -> partial Sp[kh].
//   Softmax: 512 thr: row=tid>>4, cols {cg,cg+16}; sums Sp[0]+Sp[1];
//            16-lane shfl reduce; P[32][40] bf16 (+1 self slot = "+v").
//   PV:      (rg, cw=w>>1): rows rg x channels [cw*128,+128) -> Osw
//            (32KB, XOR-chunk swizzle, conflict-free proj A-reads).
//   Proj:    wave -> out[32 x 64] at cols w*64, K=512, with explicit
//            double-buffered woutT prefetch (the loop the compiler can't
//            hoist loads across).
__global__ __launch_bounds__(512, 4)
void attn_fused(const u16* __restrict__ Q, const u16* __restrict__ Kb,
                const u16* __restrict__ Vt, const float* __restrict__ width,
                const u16* __restrict__ woutT, float* __restrict__ Out) {
  __shared__ alignas(16) u16 Osw[32 * 512];   // 32KB O, row-chunk-swizzled
  __shared__ float Sp[2][32][33];             // split-K partial scores
  __shared__ u16 P[32][40];                   // probs (pad 40)
  const int tid  = threadIdx.x;
  const int lane = tid & 63;
  const int wave = tid >> 6;      // 0..7
  const int quad = lane >> 4;
  const int lr   = lane & 15;
  const int p0   = blockIdx.x * 32;
  const int rg   = wave & 1;            // row-group (16 rows)
  const int tw   = (wave >> 1) & 1;     // phase A: score-col half
  const int kh   = wave >> 2;           // phase A: channel half
  const int cw   = wave >> 1;           // PV: 128-ch slice (0..3)
  const int prg  = p0 + rg * 16;
  const int pib  = prg & 8191;
  const int bb   = prg >> 13;

  // ---- Phase A: partial scores rows rg x cols tw*16 over channels kh*256
  {
    const u16* qb = Q  + (size_t)(prg + lr) * 512 + kh * 256 + quad * 8;
    const u16* kb = Kb + (ptrdiff_t)(prg - 8 + tw * 16 + lr) * 512 +
                    kh * 256 + quad * 8;
    floatx4 s0 = (floatx4)0.0f;
#pragma unroll
    for (int s = 0; s < 8; ++s) {
      shortx8 af = *(const shortx8*)(qb + s * 32);
      shortx8 f  = *(const shortx8*)(kb + s * 32);
      s0 = __builtin_amdgcn_mfma_f32_16x16x32_bf16(af, f, s0, 0, 0, 0);
    }
#pragma unroll
    for (int r = 0; r < 4; ++r)
      Sp[kh][rg * 16 + quad * 4 + r][tw * 16 + lr] = s0[r];
  }
  __syncthreads();

  // ---- softmax: row = tid>>4 (0..31), cols {cg, cg+16}
  {
    const int row = tid >> 4, cg = tid & 15;
    const int rr  = row & 15;                       // row within its group
    const int pibr = (p0 + (row >> 4) * 16) & 8191; // group batch offset
    const float scale = 0.044194173824159216f;      // 512^-0.5
    const float wrow = width[p0 + row];
    float sv[2]; float mx = -1e30f;
#pragma unroll
    for (int t = 0; t < 2; ++t) {
      const int col = t * 16 + cg;
      const int d  = col - rr;            // window slot 0..16 when in band
      const int jb = pibr + col - 8;      // k position within batch
      float s = Sp[0][row][col] + Sp[1][row][col];
      float rel = fabsf((float)(d - 8));
      float msk = 1.f / (1.f + __expf(-5.f * (wrow - rel)));
      float pen = (1.f - msk) * 10000.f;
      float val = (d >= 0 && d <= 16)
          ? (((unsigned)jb < 8192u ? s * scale : 0.f) - pen)
          : -1e30f;
      sv[t] = val; mx = fmaxf(mx, val);
    }
#pragma unroll
    for (int m = 8; m >= 1; m >>= 1) mx = fmaxf(mx, __shfl_xor(mx, m, 64));
    float e0 = __expf(sv[0] - mx), e1 = __expf(sv[1] - mx);
    float sum = e0 + e1;
#pragma unroll
    for (int m = 8; m >= 1; m >>= 1) sum += __shfl_xor(sum, m, 64);
    const float inv = 1.f / sum;
    // +1 at the self slot (d==8) folds the "+ v" into PV
    P[row][cg]      = f2b(e0 * inv + ((cg - rr) == 8 ? 1.f : 0.f));
    P[row][cg + 16] = f2b(e1 * inv + ((cg + 16 - rr) == 8 ? 1.f : 0.f));
  }
  __syncthreads();

  // ---- PV: wave (rg, cw): rows rg x channels [cw*128, cw*128+128)
  {
    shortx8 pf = *(const shortx8*)&P[rg * 16 + lr][quad * 8];
    const size_t cb0 = (size_t)bb * SEG + pib;      // Vt col of window slot 0
#pragma unroll
    for (int ct = 0; ct < 8; ++ct) {
      const int ch = cw * 128 + ct * 16 + lr;
      shortx8 vf = *(const shortx8*)(Vt + (size_t)ch * LV + cb0 + quad * 8);
      floatx4 o = __builtin_amdgcn_mfma_f32_16x16x32_bf16(pf, vf, (floatx4)0.0f,
                                                          0, 0, 0);
      const int c = cw * 16 + ct * 2 + (lr >> 3);   // 16B chunk 0..63
#pragma unroll
      for (int r = 0; r < 4; ++r) {
        const int row = rg * 16 + quad * 4 + r;
        Osw[row * 512 + (((c & ~7) | ((c & 7) ^ (row & 7))) << 3) + (lr & 7)] =
            f2b(o[r]);
      }
    }
  }
  __syncthreads();

  // ---- projection: wave -> out[32 x 64] at cols wave*64, K = 512,
  //      explicit double-buffered woutT prefetch
  const int wc = wave * 64;
  const u16* wbase = woutT + (size_t)(wc + lr) * 512 + quad * 8;
  floatx4 acc[2][4];
#pragma unroll
  for (int mi = 0; mi < 2; ++mi)
#pragma unroll
    for (int ni = 0; ni < 4; ++ni) acc[mi][ni] = (floatx4)0.0f;

  shortx8 bcur[4], bnxt[4];
#pragma unroll
  for (int ni = 0; ni < 4; ++ni)
    bcur[ni] = *(const shortx8*)(wbase + (size_t)ni * 16 * 512);

  for (int ksl = 0; ksl < 16; ++ksl) {
    if (ksl < 15) {
#pragma unroll
      for (int ni = 0; ni < 4; ++ni)
        bnxt[ni] = *(const shortx8*)(wbase + (size_t)ni * 16 * 512 +
                                     (ksl + 1) * 32);
    }
    shortx8 afr[2];
#pragma unroll
    for (int mi = 0; mi < 2; ++mi) {
      const int row = mi * 16 + lr;
      const int c = ksl * 4 + quad;
      afr[mi] = *(const shortx8*)
          &Osw[row * 512 + (((c & ~7) | ((c & 7) ^ (row & 7))) << 3)];
    }
#pragma unroll
    for (int mi = 0; mi < 2; ++mi)
#pragma unroll
      for (int ni = 0; ni < 4; ++ni)
        acc[mi][ni] = __builtin_amdgcn_mfma_f32_16x16x32_bf16(
            afr[mi], bcur[ni], acc[mi][ni], 0, 0, 0);
#pragma unroll
    for (int ni = 0; ni < 4; ++ni) bcur[ni] = bnxt[ni];
  }

  // ---- epilogue: direct fp32 stores (row=mi*16+quad*4+r, col=wc+ni*16+lr)
#pragma unroll
  for (int mi = 0; mi < 2; ++mi)
#pragma unroll
    for (int ni = 0; ni < 4; ++ni)
#pragma unroll
      for (int r = 0; r < 4; ++r)
        Out[(size_t)(p0 + mi * 16 + quad * 4 + r) * 512 + wc + ni * 16 + lr] =
            acc[mi][ni][r];
}

// ---------------------------------------------------------------------------
extern "C" void kernel_launch(void* const* d_in, const int* in_sizes, int n_in,
                              void* d_out, int out_size, void* d_ws, size_t ws_size,
                              hipStream_t stream) {
  const float* x       = (const float*)d_in[0];  // [2,8192,512] fp32
  const float* w_qkv   = (const float*)d_in[1];  // [512,1536]  fp32
  const float* w_width = (const float*)d_in[2];  // [512,1]     fp32
  const float* b_width = (const float*)d_in[3];  // [1]         fp32
  const float* w_out   = (const float*)d_in[4];  // [512,512]   fp32
  float* out = (float*)d_out;                    // [2,8192,512] fp32

  const int M = 16384, N3 = 1536;
  char* ws = (char*)d_ws;
  u16*   xb    = (u16*)(ws);                       // 16,777,216
  u16*   Qb    = (u16*)(ws + 16777216);            // 16,777,216
  u16*   Kb    = (u16*)(ws + 33554432 + 8192);     // 8KB guard | 16.7MB | guard
  u16*   Vt    = (u16*)(ws + 50348032);            // 512*16416*2 = 16,809,984
  u16*   wqkvT = (u16*)(ws + 67158016);            //  1,572,864
  u16*   woutT = (u16*)(ws + 68730880);            //    524,288
  float* width = (float*)(ws + 69255168);          //     65,536

  prep<<<dim3(5184), dim3(256), 0, stream>>>(x, w_width, b_width, w_qkv, w_out,
                                             xb, width, wqkvT, woutT, Vt);
  gemm_bt<1><<<dim3(M / 128, N3 / 128), dim3(256), 0, stream>>>(xb, wqkvT, Qb,
                                                                Kb, Vt);
  attn_fused<<<dim3(M / 32), dim3(512), 0, stream>>>(Qb, Kb, Vt, width, woutT,
                                                     out);
}

// Round 4
// 155.168 us; speedup vs baseline: 1.0624x; 1.0604x over previous
//
#include <hip/hip_runtime.h>

typedef unsigned short u16;
typedef unsigned int   u32;
typedef __attribute__((ext_vector_type(8))) short          shortx8;
typedef __attribute__((ext_vector_type(8))) unsigned short ushortx8;
typedef __attribute__((ext_vector_type(4))) float          floatx4;

#define AS1 __attribute__((address_space(1)))
#define AS3 __attribute__((address_space(3)))

#define SEG 8208   // 8192 + 16 pad cols per batch segment of Vt
#define LV  16416  // 2 * SEG

__device__ __forceinline__ float b2f(u16 v) {
  return __uint_as_float(((u32)v) << 16);
}
__device__ __forceinline__ u16 f2b(float f) {
  u32 u = __float_as_uint(f);
  u += 0x7FFF + ((u >> 16) & 1);   // RNE
  return (u16)(u >> 16);
}
__device__ __forceinline__ void cp16(const void* g, void* l) {
  // 16B/lane global->LDS DMA; LDS dest must be wave-uniform base + lane*16
  __builtin_amdgcn_global_load_lds((AS1 u32*)g, (AS3 u32*)l, 16, 0, 0);
}

// ---------------------------------------------------------------------------
// Fused prep: [0,4096) cast+width rows; [4096,4864) transpose w_qkv;
// [4864,5120) transpose w_out; [5120,5184) Vt pad-zeroing.
__global__ __launch_bounds__(256)
void prep(const float* __restrict__ x, const float* __restrict__ w_width,
          const float* __restrict__ b_width, const float* __restrict__ w_qkv,
          const float* __restrict__ w_out, u16* __restrict__ xb,
          float* __restrict__ width, u16* __restrict__ wqkvT,
          u16* __restrict__ woutT, u16* __restrict__ Vt) {
  __shared__ u16 tile[32][33];
  const int b = blockIdx.x;
  if (b < 4096) {                    // ---- cast x -> bf16, compute width
    const int lane = threadIdx.x & 63;
    const int row  = b * 4 + (threadIdx.x >> 6);
    const float* xp = x + (size_t)row * 512 + lane * 8;
    floatx4 v0 = *(const floatx4*)xp;
    floatx4 v1 = *(const floatx4*)(xp + 4);
    floatx4 w0 = *(const floatx4*)(w_width + lane * 8);
    floatx4 w1 = *(const floatx4*)(w_width + lane * 8 + 4);
    float s = 0.f;
    ushortx8 o;
#pragma unroll
    for (int j = 0; j < 4; ++j) {
      s += v0[j] * w0[j] + v1[j] * w1[j];
      o[j] = f2b(v0[j]); o[4 + j] = f2b(v1[j]);
    }
    *(ushortx8*)(xb + (size_t)row * 512 + lane * 8) = o;
#pragma unroll
    for (int m = 32; m >= 1; m >>= 1) s += __shfl_xor(s, m, 64);
    if (lane == 0)
      width[row] = 16.f / (1.f + __expf(-(s + b_width[0]))) + 1.f;
  } else if (b < 5120) {             // ---- weight transposes (fp32 -> bf16^T)
    const float* in; u16* out; int R, C, t;
    if (b < 4864) { in = w_qkv; out = wqkvT; R = 512; C = 1536; t = b - 4096; }
    else          { in = w_out; out = woutT; R = 512; C = 512;  t = b - 4864; }
    const int nbx = C / 32;
    const int cb = (t % nbx) * 32;
    const int rb = (t / nbx) * 32;
    const int tx = threadIdx.x & 31;
    const int ty = threadIdx.x >> 5;
#pragma unroll
    for (int i = 0; i < 32; i += 8)
      tile[ty + i][tx] = f2b(in[(size_t)(rb + ty + i) * C + cb + tx]);
    __syncthreads();
#pragma unroll
    for (int i = 0; i < 32; i += 8)
      out[(size_t)(cb + ty + i) * R + rb + tx] = tile[tx][ty + i];
  } else {                           // ---- Vt pad-column zeroing
    const int idx = (b - 5120) * 256 + threadIdx.x;  // 512 ch * 32 pad cols
    const int ch = idx >> 5;
    const int k  = idx & 31;
    const int seg = k >> 4;
    const int j   = k & 15;
    const int col = seg * SEG + (j < 8 ? j : 8192 + j);
    Vt[(size_t)ch * LV + col] = 0;
  }
}

// ---------------------------------------------------------------------------
// C = A[M][512] @ Bt[N][512]^T, bf16 in, fp32 acc.  128x128 tile, BK=64,
// XOR-swizzled LDS staging, LDS-shuffled coalesced epilogues.
// MODE 1: N=1536, scatter epilogue -> Qb / Kb / Vt(transposed, batch-padded).
// MODE 2: N=512,  fp32 C (ldc=512), direct stores.  (unused after proj fusion)
template <int MODE>
__global__ __launch_bounds__(256, 3)
void gemm_bt(const u16* __restrict__ A, const u16* __restrict__ Bt,
             void* __restrict__ C0, u16* __restrict__ Kb, u16* __restrict__ Vt) {
  const int K = 512;
  __shared__ alignas(16) u16 lds[17408];        // 34,816 B (union)
  u16* As = lds;                                // 8192 u16 (128 x 64)
  u16* Bs = lds + 8192;                         // 8192 u16
  const int tid  = threadIdx.x;
  const int lane = tid & 63;
  const int wave = tid >> 6;
  const int quad = lane >> 4;
  const int lr   = lane & 15;
  const int row0 = blockIdx.x * 128;
  const int col0 = blockIdx.y * 128;
  const int wr   = (wave >> 1) * 64;
  const int wc   = (wave & 1) * 64;

  floatx4 acc[4][4];
#pragma unroll
  for (int i = 0; i < 4; ++i)
#pragma unroll
    for (int j = 0; j < 4; ++j) acc[i][j] = (floatx4)0.0f;

  // chunk c = p*256+tid -> LDS slot c; row c>>3, phys colblk (c&7)^(row&7)
  int srow[4], scol[4];
#pragma unroll
  for (int p = 0; p < 4; ++p) {
    int c = p * 256 + tid;
    srow[p] = c >> 3;
    scol[p] = ((c & 7) ^ (srow[p] & 7)) * 8;
  }
  const int swz = lr & 7;

  for (int k0 = 0; k0 < K; k0 += 64) {
#pragma unroll
    for (int p = 0; p < 4; ++p)
      cp16(A + (size_t)(row0 + srow[p]) * K + k0 + scol[p], &As[(p * 256 + tid) * 8]);
#pragma unroll
    for (int p = 0; p < 4; ++p)
      cp16(Bt + (size_t)(col0 + srow[p]) * K + k0 + scol[p], &Bs[(p * 256 + tid) * 8]);
    __syncthreads();

#pragma unroll
    for (int ks = 0; ks < 2; ++ks) {
      shortx8 af[4], bf[4];
#pragma unroll
      for (int mi = 0; mi < 4; ++mi)
        af[mi] = *(const shortx8*)
            &As[((wr + mi * 16 + lr) * 8 + ((ks * 4 + quad) ^ swz)) * 8];
#pragma unroll
      for (int ni = 0; ni < 4; ++ni)
        bf[ni] = *(const shortx8*)
            &Bs[((wc + ni * 16 + lr) * 8 + ((ks * 4 + quad) ^ swz)) * 8];
#pragma unroll
      for (int mi = 0; mi < 4; ++mi)
#pragma unroll
        for (int ni = 0; ni < 4; ++ni)
          acc[mi][ni] = __builtin_amdgcn_mfma_f32_16x16x32_bf16(
              af[mi], bf[ni], acc[mi][ni], 0, 0, 0);
    }
    __syncthreads();
  }

  // C/D layout: col = lane&15, row = quad*4 + reg  [verified m89/m91]
  if constexpr (MODE == 1) {
    if (col0 < 1024) {               // ---- Q or K: row-major LDS, coalesced out
      u16* dst = (col0 < 512) ? (u16*)C0 : Kb;
      const int cb = col0 & 511;
#pragma unroll
      for (int mi = 0; mi < 4; ++mi)
#pragma unroll
        for (int ni = 0; ni < 4; ++ni)
#pragma unroll
          for (int r = 0; r < 4; ++r)
            lds[(wr + mi * 16 + quad * 4 + r) * 136 + wc + ni * 16 + lr] =
                f2b(acc[mi][ni][r]);
      __syncthreads();
      const int rr = tid >> 4, cc = (tid & 15) * 8;
#pragma unroll
      for (int it = 0; it < 8; ++it) {
        int row = it * 16 + rr;
        *(ushortx8*)(dst + (size_t)(row0 + row) * 512 + cb + cc) =
            *(const ushortx8*)&lds[row * 136 + cc];
      }
    } else {                         // ---- V: transposed LDS, coalesced out
      const int cb = col0 - 1024;
      const int bb = row0 >> 13, pib0 = row0 & 8191;
#pragma unroll
      for (int mi = 0; mi < 4; ++mi)
#pragma unroll
        for (int ni = 0; ni < 4; ++ni)
#pragma unroll
          for (int r = 0; r < 4; ++r)
            lds[(wc + ni * 16 + lr) * 136 + wr + mi * 16 + quad * 4 + r] =
                f2b(acc[mi][ni][r]);
      __syncthreads();
      const int rr = tid >> 4, cc = (tid & 15) * 8;
#pragma unroll
      for (int it = 0; it < 8; ++it) {
        int chl = it * 16 + rr;
        ushortx8 v = *(const ushortx8*)&lds[chl * 136 + cc];
        *(ushortx8*)(Vt + (size_t)(cb + chl) * LV + (size_t)bb * SEG + 8 + pib0 + cc) = v;
      }
    }
  } else {
    float* Cf = (float*)C0;
#pragma unroll
    for (int mi = 0; mi < 4; ++mi)
#pragma unroll
      for (int ni = 0; ni < 4; ++ni)
#pragma unroll
        for (int r = 0; r < 4; ++r) {
          int row = row0 + wr + mi * 16 + quad * 4 + r;
          int col = col0 + wc + ni * 16 + lr;
          Cf[(size_t)row * 512 + col] = acc[mi][ni][r];
        }
  }
}

// ---------------------------------------------------------------------------
// Fused local attention + output projection, v4 = v1 structure + deep ILP.
// v1 (64 pos/block, 256 blocks, 4 fat waves, in-reg softmax, 2-half proj)
// measured fastest of all variants (< the 42us fills; v2 51.5, v3 48.2 --
// splitting work across more waves added barriers/LDS round-trips and lost).
// At grid=256 (1 block/CU, 1 wave/SIMD) VGPRs are free up to ~500/wave, so
// v4 spends them on memory-level parallelism instead of occupancy:
//   * all 16 Vt half-0 loads hoisted to kernel start (hide ~900cy HBM under
//     Phase A + softmax),
//   * 16 Vt half-1 loads issued before proj(h0) (hide under 256 MFMAs),
//   * explicit 1-deep woutT prefetch in proj (v3's attempt was folded by
//     the compiler under the (512,4) reg cap -- VGPR_Count=52 proved it).
__global__ __launch_bounds__(256, 1)
void attn_fused(const u16* __restrict__ Q, const u16* __restrict__ Kb,
                const u16* __restrict__ Vt, const float* __restrict__ width,
                const u16* __restrict__ woutT, float* __restrict__ Out) {
  __shared__ alignas(16) u16 Osw[64 * 256];   // 32KB: half of O, swizzled
  __shared__ alignas(16) u16 P[4][16][32];    // 4KB: per-wave P (A-layout)
  const int tid  = threadIdx.x;
  const int lane = tid & 63;
  const int wave = tid >> 6;
  const int quad = lane >> 4;
  const int lr   = lane & 15;
  const int p0   = blockIdx.x * 64;
  const int pw   = p0 + wave * 16;
  const int pibw = pw & 8191;
  const int bb   = pw >> 13;
  const size_t cb0 = (size_t)bb * SEG + pibw;   // Vt col of window slot 0

  // ---- hoisted Vt half-0 loads (independent of all other phases)
  shortx8 vfA[16];
#pragma unroll
  for (int ctl = 0; ctl < 16; ++ctl)
    vfA[ctl] = *(const shortx8*)(Vt + (size_t)(ctl * 16 + lr) * LV +
                                 cb0 + quad * 8);

  // ---- Phase A: scores 16x32 over all 512 channels (this wave's rows)
  floatx4 s0 = (floatx4)0.0f, s1 = (floatx4)0.0f;
#pragma unroll 4
  for (int s = 0; s < 16; ++s) {
    const int k0 = s * 32 + quad * 8;
    shortx8 af = *(const shortx8*)(Q  + (size_t)(pw + lr) * 512 + k0);
    shortx8 f0 = *(const shortx8*)(Kb + (ptrdiff_t)(pw - 8 + lr) * 512 + k0);
    shortx8 f1 = *(const shortx8*)(Kb + (ptrdiff_t)(pw + 8 + lr) * 512 + k0);
    s0 = __builtin_amdgcn_mfma_f32_16x16x32_bf16(af, f0, s0, 0, 0, 0);
    s1 = __builtin_amdgcn_mfma_f32_16x16x32_bf16(af, f1, s1, 0, 0, 0);
  }

  // ---- Softmax in-register.  Thread holds rows quad*4+r, cols {lr, lr+16}.
  {
    const float scale = 0.044194173824159216f;   // 512^-0.5
    floatx4 wv = *(const floatx4*)(width + pw + quad * 4);
#pragma unroll
    for (int r = 0; r < 4; ++r) {
      const int row = quad * 4 + r;
      const int d0  = lr - row;            // window slot of col lr
      const int d1  = d0 + 16;             // window slot of col lr+16
      const int jb0 = pibw + lr - 8;       // k position within batch
      const int jb1 = jb0 + 16;
      float rel0 = fabsf((float)(d0 - 8));
      float rel1 = fabsf((float)(d1 - 8));
      float mk0 = 1.f / (1.f + __expf(-5.f * (wv[r] - rel0)));
      float mk1 = 1.f / (1.f + __expf(-5.f * (wv[r] - rel1)));
      float val0 = (d0 >= 0)
          ? (((unsigned)jb0 < 8192u ? s0[r] * scale : 0.f) - (1.f - mk0) * 10000.f)
          : -1e30f;
      float val1 = (d1 <= 16)
          ? (((unsigned)jb1 < 8192u ? s1[r] * scale : 0.f) - (1.f - mk1) * 10000.f)
          : -1e30f;
      float mx = fmaxf(val0, val1);
#pragma unroll
      for (int m = 8; m >= 1; m >>= 1) mx = fmaxf(mx, __shfl_xor(mx, m, 64));
      float e0 = __expf(val0 - mx), e1 = __expf(val1 - mx);
      float sum = e0 + e1;
#pragma unroll
      for (int m = 8; m >= 1; m >>= 1) sum += __shfl_xor(sum, m, 64);
      const float inv = 1.f / sum;
      // +1 at the self slot (d==8) folds the "+ v" into PV
      P[wave][row][lr]      = f2b(e0 * inv + (d0 == 8 ? 1.f : 0.f));
      P[wave][row][lr + 16] = f2b(e1 * inv + (d1 == 8 ? 1.f : 0.f));
    }
  }
  // P write->read is same-wave: DS ops are in-order per wave, no barrier.
  shortx8 pf = *(const shortx8*)&P[wave][lr][quad * 8];  // A[m=lr][k=quad*8+j]

  const int wc = wave * 128;
  floatx4 acc[4][8];
#pragma unroll
  for (int mi = 0; mi < 4; ++mi)
#pragma unroll
    for (int ni = 0; ni < 8; ++ni) acc[mi][ni] = (floatx4)0.0f;

  // ---- issue Vt half-1 loads now; they complete during proj(h0)
  shortx8 vfB[16];
#pragma unroll
  for (int ctl = 0; ctl < 16; ++ctl)
    vfB[ctl] = *(const shortx8*)(Vt + (size_t)(256 + ctl * 16 + lr) * LV +
                                 cb0 + quad * 8);

  // ---- PV(h0): o C-layout (row=pos, col=ch) -> swizzled Osw
#pragma unroll
  for (int ctl = 0; ctl < 16; ++ctl) {
    floatx4 o = __builtin_amdgcn_mfma_f32_16x16x32_bf16(pf, vfA[ctl],
                                                        (floatx4)0.0f, 0, 0, 0);
    const int c = ctl * 2 + (lr >> 3);   // 16B chunk 0..31 within half
#pragma unroll
    for (int r = 0; r < 4; ++r) {
      const int row = wave * 16 + quad * 4 + r;
      Osw[row * 256 + (((c & ~7) | ((c & 7) ^ (row & 7))) << 3) + (lr & 7)] =
          f2b(o[r]);
    }
  }
  __syncthreads();   // Osw h0 complete (cross-wave rows needed below)

  // ---- proj(h0): out[64 x 128] per wave += O[:, 0:256] @ woutT[wc.., 0:256]
  {
    shortx8 bcur[8], bnxt[8];
#pragma unroll
    for (int ni = 0; ni < 8; ++ni)
      bcur[ni] = *(const shortx8*)(woutT + (size_t)(wc + ni * 16 + lr) * 512 +
                                   quad * 8);
    for (int ksl = 0; ksl < 8; ++ksl) {
      if (ksl < 7) {
#pragma unroll
        for (int ni = 0; ni < 8; ++ni)
          bnxt[ni] = *(const shortx8*)(woutT +
                       (size_t)(wc + ni * 16 + lr) * 512 +
                       (ksl + 1) * 32 + quad * 8);
      }
      shortx8 afr[4];
#pragma unroll
      for (int mi = 0; mi < 4; ++mi) {
        const int row = mi * 16 + lr;
        const int c = ksl * 4 + quad;
        afr[mi] = *(const shortx8*)
            &Osw[row * 256 + (((c & ~7) | ((c & 7) ^ (row & 7))) << 3)];
      }
#pragma unroll
      for (int mi = 0; mi < 4; ++mi)
#pragma unroll
        for (int ni = 0; ni < 8; ++ni)
          acc[mi][ni] = __builtin_amdgcn_mfma_f32_16x16x32_bf16(
              afr[mi], bcur[ni], acc[mi][ni], 0, 0, 0);
      if (ksl < 7) {
#pragma unroll
        for (int ni = 0; ni < 8; ++ni) bcur[ni] = bnxt[ni];
      }
    }
  }
  __syncthreads();   // drain Osw reads before h1 overwrites

  // ---- PV(h1) using prefetched vfB
#pragma unroll
  for (int ctl = 0; ctl < 16; ++ctl) {
    floatx4 o = __builtin_amdgcn_mfma_f32_16x16x32_bf16(pf, vfB[ctl],
                                                        (floatx4)0.0f, 0, 0, 0);
    const int c = ctl * 2 + (lr >> 3);
#pragma unroll
    for (int r = 0; r < 4; ++r) {
      const int row = wave * 16 + quad * 4 + r;
      Osw[row * 256 + (((c & ~7) | ((c & 7) ^ (row & 7))) << 3) + (lr & 7)] =
          f2b(o[r]);
    }
  }
  __syncthreads();

  // ---- proj(h1)
  {
    shortx8 bcur[8], bnxt[8];
#pragma unroll
    for (int ni = 0; ni < 8; ++ni)
      bcur[ni] = *(const shortx8*)(woutT + (size_t)(wc + ni * 16 + lr) * 512 +
                                   256 + quad * 8);
    for (int ksl = 0; ksl < 8; ++ksl) {
      if (ksl < 7) {
#pragma unroll
        for (int ni = 0; ni < 8; ++ni)
          bnxt[ni] = *(const shortx8*)(woutT +
                       (size_t)(wc + ni * 16 + lr) * 512 +
                       256 + (ksl + 1) * 32 + quad * 8);
      }
      shortx8 afr[4];
#pragma unroll
      for (int mi = 0; mi < 4; ++mi) {
        const int row = mi * 16 + lr;
        const int c = ksl * 4 + quad;
        afr[mi] = *(const shortx8*)
            &Osw[row * 256 + (((c & ~7) | ((c & 7) ^ (row & 7))) << 3)];
      }
#pragma unroll
      for (int mi = 0; mi < 4; ++mi)
#pragma unroll
        for (int ni = 0; ni < 8; ++ni)
          acc[mi][ni] = __builtin_amdgcn_mfma_f32_16x16x32_bf16(
              afr[mi], bcur[ni], acc[mi][ni], 0, 0, 0);
      if (ksl < 7) {
#pragma unroll
        for (int ni = 0; ni < 8; ++ni) bcur[ni] = bnxt[ni];
      }
    }
  }

  // ---- epilogue: direct fp32 stores (row=mi*16+quad*4+r, col=wc+ni*16+lr)
#pragma unroll
  for (int mi = 0; mi < 4; ++mi)
#pragma unroll
    for (int ni = 0; ni < 8; ++ni)
#pragma unroll
      for (int r = 0; r < 4; ++r)
        Out[(size_t)(p0 + mi * 16 + quad * 4 + r) * 512 + wc + ni * 16 + lr] =
            acc[mi][ni][r];
}

// ---------------------------------------------------------------------------
extern "C" void kernel_launch(void* const* d_in, const int* in_sizes, int n_in,
                              void* d_out, int out_size, void* d_ws, size_t ws_size,
                              hipStream_t stream) {
  const float* x       = (const float*)d_in[0];  // [2,8192,512] fp32
  const float* w_qkv   = (const float*)d_in[1];  // [512,1536]  fp32
  const float* w_width = (const float*)d_in[2];  // [512,1]     fp32
  const float* b_width = (const float*)d_in[3];  // [1]         fp32
  const float* w_out   = (const float*)d_in[4];  // [512,512]   fp32
  float* out = (float*)d_out;                    // [2,8192,512] fp32

  const int M = 16384, N3 = 1536;
  char* ws = (char*)d_ws;
  u16*   xb    = (u16*)(ws);                       // 16,777,216
  u16*   Qb    = (u16*)(ws + 16777216);            // 16,777,216
  u16*   Kb    = (u16*)(ws + 33554432 + 8192);     // 8KB guard | 16.7MB | guard
  u16*   Vt    = (u16*)(ws + 50348032);            // 512*16416*2 = 16,809,984
  u16*   wqkvT = (u16*)(ws + 67158016);            //  1,572,864
  u16*   woutT = (u16*)(ws + 68730880);            //    524,288
  float* width = (float*)(ws + 69255168);          //     65,536

  prep<<<dim3(5184), dim3(256), 0, stream>>>(x, w_width, b_width, w_qkv, w_out,
                                             xb, width, wqkvT, woutT, Vt);
  gemm_bt<1><<<dim3(M / 128, N3 / 128), dim3(256), 0, stream>>>(xb, wqkvT, Qb,
                                                                Kb, Vt);
  attn_fused<<<dim3(M / 64), dim3(256), 0, stream>>>(Qb, Kb, Vt, width, woutT,
                                                     out);
}